// Round 6
// baseline (242.967 us; speedup 1.0000x reference)
//
#include <hip/hip_runtime.h>
#include <math.h>

#define BB 512
#define NN 252
#define CC 256
#define NW 16   // waves per block (1024 threads)
#define MAGIC 0x5A5A5A5Au

typedef float vf4 __attribute__((ext_vector_type(4)));

// ws layout: float part[5][512]; unsigned flag[512]. No init needed:
// poison 0xAAAAAAAA != MAGIC, and part[] slots are guarded by flag[].

__global__ __launch_bounds__(1024, 8) void detloss_fused(const float* __restrict__ outp,
                                                         const float* __restrict__ tgtp,
                                                         float* __restrict__ part,
                                                         unsigned* __restrict__ flag,
                                                         float* __restrict__ outv) {
    const int tid = threadIdx.x;
    const int lane = tid & 63;

    // ---------------- Reducer block: spin on flags, reduce, write out ----------------
    if (blockIdx.x == BB) {
        if (tid < BB) {
            while (__hip_atomic_load(&flag[tid], __ATOMIC_ACQUIRE,
                                     __HIP_MEMORY_SCOPE_AGENT) != MAGIC) { }
        }
        __syncthreads();
        __shared__ float s_red[5];
        if (tid < 5) s_red[tid] = 0.f;
        __syncthreads();
        if (tid < BB) {
            float v0 = __hip_atomic_load(&part[0 * BB + tid], __ATOMIC_RELAXED, __HIP_MEMORY_SCOPE_AGENT);
            float v1 = __hip_atomic_load(&part[1 * BB + tid], __ATOMIC_RELAXED, __HIP_MEMORY_SCOPE_AGENT);
            float v2 = __hip_atomic_load(&part[2 * BB + tid], __ATOMIC_RELAXED, __HIP_MEMORY_SCOPE_AGENT);
            float v3 = __hip_atomic_load(&part[3 * BB + tid], __ATOMIC_RELAXED, __HIP_MEMORY_SCOPE_AGENT);
            float v4 = __hip_atomic_load(&part[4 * BB + tid], __ATOMIC_RELAXED, __HIP_MEMORY_SCOPE_AGENT);
            #pragma unroll
            for (int off = 32; off > 0; off >>= 1) {
                v0 += __shfl_down(v0, off);
                v1 += __shfl_down(v1, off);
                v2 += __shfl_down(v2, off);
                v3 += __shfl_down(v3, off);
                v4 += __shfl_down(v4, off);
            }
            if (lane == 0) {
                atomicAdd(&s_red[0], v0);
                atomicAdd(&s_red[1], v1);
                atomicAdd(&s_red[2], v2);
                atomicAdd(&s_red[3], v3);
                atomicAdd(&s_red[4], v4);
            }
        }
        __syncthreads();
        if (tid == 0) {
            const float inv = 1.0f / (float)(BB * NN);
            const float bce = s_red[0] * inv;
            const float ce  = s_red[1] * inv;
            const float lx  = s_red[2] * inv;
            const float ly  = s_red[3] * inv;
            const float lwh = s_red[4] * inv;
            const float mse = lx + ly + 2.f * lwh;
            outv[0] = 10.f * mse + bce + 0.5f * (1.f - bce) + ce;
        }
        return;
    }

    // ---------------- Worker blocks ----------------
    __shared__ float s_c1[NN], s_c2[NN], s_c3[NN];
    __shared__ float s_diag[NN], s_row0[NN];
    __shared__ float s_part[NW * NN];
    __shared__ float s_red[5];
    __shared__ short s_rows[NN];      // compacted masked-row indices
    __shared__ int s_fill[NN];
    __shared__ int s_nm;              // number of masked rows

    const int b = blockIdx.x;
    const float* ob = outp + (size_t)b * NN * CC;
    const float* tb = tgtp + (size_t)b * NN * CC;

    if (tid < NN) {
        s_c1[tid] = 0.f; s_c2[tid] = 0.f; s_c3[tid] = 0.f;
        s_fill[tid] = 0;
    }
    if (tid < 5) s_red[tid] = 0.f;
    if (tid == 0) s_nm = 0;
    __syncthreads();

    float bce_c = 0.f, ce_c = 0.f, lx_c = 0.f, ly_c = 0.f, lwh_c = 0.f;
    float4 o4 = make_float4(0.f, 0.f, 0.f, 0.f);
    bool m = false;

    // Phase A: BCE + scatter target coords by class (per-batch permutation) + row compaction.
    if (tid < NN) {
        const float4 t4 = *(const float4*)(tb + (size_t)tid * CC);   // t0..t3
        const float tcls = tb[(size_t)tid * CC + 4];                 // class id (exact small int)
        o4 = *(const float4*)(ob + (size_t)tid * CC);                // p, x, y, wh
        const float t0 = t4.x;
        bce_c = -(t0 * __logf(o4.x) + (1.f - t0) * log1pf(-o4.x));
        m = (t0 != 0.f);
        if (m) {
            const int j = (int)tcls;              // unique per masked row
            s_c1[j] = t4.y; s_c2[j] = t4.z; s_c3[j] = t4.w; s_fill[j] = 1;
            const int slot = atomicAdd(&s_nm, 1);
            s_rows[slot] = (short)tid;
        }
    }
    __syncthreads();

    // Phase A2: MSE terms at slot j = tid + one-shot diag/row0 capture.
    if (tid < NN) {
        const float f1 = m ? o4.y : 0.f;
        const float f2 = m ? o4.z : 0.f;
        const float f3 = m ? o4.w : 0.f;
        const float d1 = f1 - s_c1[tid];
        const float d2 = f2 - s_c2[tid];
        const float d3 = sqrtf(f3) - sqrtf(s_c3[tid]);
        lx_c = d1 * d1; ly_c = d2 * d2; lwh_c = d3 * d3;

        // diag logit: filtered[b,tid,4+tid] (predicated gather)
        s_diag[tid] = m ? ob[(size_t)tid * CC + 4 + tid] : 0.f;
        // row-0 logits: filtered[b,0,4+tid] (coalesced)
        const bool m0 = (tb[0] != 0.f);
        s_row0[tid] = m0 ? ob[4 + tid] : 0.f;
    }

    // Phase B: pure streaming loop over compacted masked rows.
    // Lane l owns logit channels 4l..4l+3 (float4); waves stride over the row list.
    const int wave = tid >> 6;
    const int nm = s_nm;
    if (lane < 63) {
        const float* base = ob + 4 + 4 * lane;
        float sx = 0.f, sy = 0.f, sz = 0.f, sw = 0.f;
        for (int i = wave; i < nm; i += NW) {
            const int n = s_rows[i];
            const vf4 v = __builtin_nontemporal_load((const vf4*)(base + (size_t)n * CC));
            sx += __expf(v.x);
            sy += __expf(v.y);
            sz += __expf(v.z);
            sw += __expf(v.w);
        }
        const int o = wave * NN + 4 * lane;
        s_part[o+0] = sx; s_part[o+1] = sy; s_part[o+2] = sz; s_part[o+3] = sw;
    }
    __syncthreads();

    // Phase C: combine partials -> lse -> ce contribution per channel.
    if (tid < NN) {
        float s = (float)(NN - nm);            // unmasked rows contribute exp(0)=1
        #pragma unroll
        for (int w = 0; w < NW; ++w) s += s_part[w * NN + tid];
        const float lse = __logf(s);
        ce_c = lse - (s_fill[tid] ? s_diag[tid] : s_row0[tid]);
    }

    // Block reduction: wave shuffle -> LDS atomics -> publish partials + flag.
    #pragma unroll
    for (int off = 32; off > 0; off >>= 1) {
        bce_c += __shfl_down(bce_c, off);
        ce_c  += __shfl_down(ce_c,  off);
        lx_c  += __shfl_down(lx_c,  off);
        ly_c  += __shfl_down(ly_c,  off);
        lwh_c += __shfl_down(lwh_c, off);
    }
    if (lane == 0) {
        atomicAdd(&s_red[0], bce_c);
        atomicAdd(&s_red[1], ce_c);
        atomicAdd(&s_red[2], lx_c);
        atomicAdd(&s_red[3], ly_c);
        atomicAdd(&s_red[4], lwh_c);
    }
    __syncthreads();
    if (tid < 5) {
        __hip_atomic_store(&part[tid * BB + b], s_red[tid],
                           __ATOMIC_RELAXED, __HIP_MEMORY_SCOPE_AGENT);
    }
    __syncthreads();   // drains vmcnt: partial stores complete before flag
    if (tid == 0) {
        __hip_atomic_store(&flag[b], MAGIC, __ATOMIC_RELEASE, __HIP_MEMORY_SCOPE_AGENT);
    }
}

extern "C" void kernel_launch(void* const* d_in, const int* in_sizes, int n_in,
                              void* d_out, int out_size, void* d_ws, size_t ws_size,
                              hipStream_t stream) {
    const float* outp = (const float*)d_in[0];
    const float* tgtp = (const float*)d_in[1];
    float* part = (float*)d_ws;                  // 5*512 floats
    unsigned* flag = (unsigned*)(part + 5 * BB); // 512 flags
    detloss_fused<<<BB + 1, 1024, 0, stream>>>(outp, tgtp, part, flag, (float*)d_out);
}

// Round 7
// 237.507 us; speedup vs baseline: 1.0230x; 1.0230x over previous
//
#include <hip/hip_runtime.h>
#include <math.h>

#define BB 512
#define NN 252
#define CC 256
#define NW 16   // waves per block (1024 threads)

typedef float vf4 __attribute__((ext_vector_type(4)));

// ws layout: float part[5][512]  (partial sums per block, no init required)

__global__ __launch_bounds__(1024, 8) void detloss_main(const float* __restrict__ outp,
                                                        const float* __restrict__ tgtp,
                                                        float* __restrict__ part) {
    __shared__ float s_c1[NN], s_c2[NN], s_c3[NN];
    __shared__ float s_diag[NN], s_row0[NN];
    __shared__ float s_part[NW * NN];
    __shared__ float s_red[5];
    __shared__ short s_rows[NN];      // compacted masked-row indices
    __shared__ int s_fill[NN];
    __shared__ int s_nm;              // number of masked rows

    const int b = blockIdx.x;
    const int tid = threadIdx.x;
    const float* ob = outp + (size_t)b * NN * CC;
    const float* tb = tgtp + (size_t)b * NN * CC;

    if (tid < NN) {
        s_c1[tid] = 0.f; s_c2[tid] = 0.f; s_c3[tid] = 0.f;
        s_diag[tid] = 0.f; s_row0[tid] = 0.f; s_fill[tid] = 0;
    }
    if (tid < 5) s_red[tid] = 0.f;
    if (tid == 0) s_nm = 0;
    __syncthreads();

    float bce_c = 0.f, ce_c = 0.f, lx_c = 0.f, ly_c = 0.f, lwh_c = 0.f;
    float4 o4 = make_float4(0.f, 0.f, 0.f, 0.f);
    bool m = false;

    // Phase A: BCE + scatter target coords by class (per-batch permutation) + row compaction.
    if (tid < NN) {
        const float4 t4 = *(const float4*)(tb + (size_t)tid * CC);   // t0..t3
        const float tcls = tb[(size_t)tid * CC + 4];                 // class id (exact small int)
        o4 = *(const float4*)(ob + (size_t)tid * CC);                // p, x, y, wh
        const float t0 = t4.x;
        bce_c = -(t0 * __logf(o4.x) + (1.f - t0) * log1pf(-o4.x));
        m = (t0 != 0.f);
        if (m) {
            const int j = (int)tcls;              // unique per masked row
            s_c1[j] = t4.y; s_c2[j] = t4.z; s_c3[j] = t4.w; s_fill[j] = 1;
            const int slot = atomicAdd(&s_nm, 1);
            s_rows[slot] = (short)tid;
        }
    }
    __syncthreads();

    // Phase A2: MSE terms at slot j = tid.
    if (tid < NN) {
        const float f1 = m ? o4.y : 0.f;
        const float f2 = m ? o4.z : 0.f;
        const float f3 = m ? o4.w : 0.f;
        const float d1 = f1 - s_c1[tid];
        const float d2 = f2 - s_c2[tid];
        const float d3 = sqrtf(f3) - sqrtf(s_c3[tid]);
        lx_c = d1 * d1; ly_c = d2 * d2; lwh_c = d3 * d3;
    }

    // Phase B: branch-free streaming over compacted masked rows.
    // Lane l owns logit channels 4l..4l+3 (float4); waves stride over the row list.
    const int wave = tid >> 6;
    const int lane = tid & 63;
    const int nm = s_nm;
    if (lane < 63) {
        const float* base = ob + 4 + 4 * lane;
        float sx = 0.f, sy = 0.f, sz = 0.f, sw = 0.f;
        for (int i = wave; i < nm; i += NW) {
            const int n = s_rows[i];
            const vf4 v = __builtin_nontemporal_load((const vf4*)(base + (size_t)n * CC));
            sx += __expf(v.x);
            sy += __expf(v.y);
            sz += __expf(v.z);
            sw += __expf(v.w);
            if ((n >> 2) == lane) {            // diag logit x[n, n]
                const int r = n & 3;
                s_diag[n] = (r == 0) ? v.x : (r == 1) ? v.y : (r == 2) ? v.z : v.w;
            }
            if (n == 0) {                      // row-0 logits (for unfilled slots)
                s_row0[4*lane+0] = v.x; s_row0[4*lane+1] = v.y;
                s_row0[4*lane+2] = v.z; s_row0[4*lane+3] = v.w;
            }
        }
        const int o = wave * NN + 4 * lane;
        s_part[o+0] = sx; s_part[o+1] = sy; s_part[o+2] = sz; s_part[o+3] = sw;
    }
    __syncthreads();

    // Phase C: combine partials -> lse -> ce contribution per channel.
    if (tid < NN) {
        float s = (float)(NN - nm);            // unmasked rows contribute exp(0)=1
        #pragma unroll
        for (int w = 0; w < NW; ++w) s += s_part[w * NN + tid];
        const float lse = __logf(s);
        ce_c = lse - (s_fill[tid] ? s_diag[tid] : s_row0[tid]);
    }

    // Block reduction: wave shuffle -> LDS atomics -> per-block partials (no global atomics).
    #pragma unroll
    for (int off = 32; off > 0; off >>= 1) {
        bce_c += __shfl_down(bce_c, off);
        ce_c  += __shfl_down(ce_c,  off);
        lx_c  += __shfl_down(lx_c,  off);
        ly_c  += __shfl_down(ly_c,  off);
        lwh_c += __shfl_down(lwh_c, off);
    }
    if (lane == 0) {
        atomicAdd(&s_red[0], bce_c);
        atomicAdd(&s_red[1], ce_c);
        atomicAdd(&s_red[2], lx_c);
        atomicAdd(&s_red[3], ly_c);
        atomicAdd(&s_red[4], lwh_c);
    }
    __syncthreads();
    if (tid < 5) part[tid * BB + b] = s_red[tid];
}

__global__ __launch_bounds__(512) void detloss_final(const float* __restrict__ part,
                                                     float* __restrict__ outv) {
    __shared__ float s_red[5];
    const int tid = threadIdx.x;
    const int lane = tid & 63;
    if (tid < 5) s_red[tid] = 0.f;
    __syncthreads();

    float v0 = part[0 * BB + tid];
    float v1 = part[1 * BB + tid];
    float v2 = part[2 * BB + tid];
    float v3 = part[3 * BB + tid];
    float v4 = part[4 * BB + tid];
    #pragma unroll
    for (int off = 32; off > 0; off >>= 1) {
        v0 += __shfl_down(v0, off);
        v1 += __shfl_down(v1, off);
        v2 += __shfl_down(v2, off);
        v3 += __shfl_down(v3, off);
        v4 += __shfl_down(v4, off);
    }
    if (lane == 0) {
        atomicAdd(&s_red[0], v0);
        atomicAdd(&s_red[1], v1);
        atomicAdd(&s_red[2], v2);
        atomicAdd(&s_red[3], v3);
        atomicAdd(&s_red[4], v4);
    }
    __syncthreads();
    if (tid == 0) {
        const float inv = 1.0f / (float)(BB * NN);
        const float bce = s_red[0] * inv;
        const float ce  = s_red[1] * inv;
        const float lx  = s_red[2] * inv;
        const float ly  = s_red[3] * inv;
        const float lwh = s_red[4] * inv;
        const float mse = lx + ly + 2.f * lwh;
        outv[0] = 10.f * mse + bce + 0.5f * (1.f - bce) + ce;
    }
}

extern "C" void kernel_launch(void* const* d_in, const int* in_sizes, int n_in,
                              void* d_out, int out_size, void* d_ws, size_t ws_size,
                              hipStream_t stream) {
    const float* outp = (const float*)d_in[0];
    const float* tgtp = (const float*)d_in[1];
    float* part = (float*)d_ws;     // 5*512 floats, fully written by detloss_main
    detloss_main<<<BB, 1024, 0, stream>>>(outp, tgtp, part);
    detloss_final<<<1, 512, 0, stream>>>(part, (float*)d_out);
}